// Round 1
// baseline (1777.914 us; speedup 1.0000x reference)
//
#include <hip/hip_runtime.h>
#include <hip/hip_fp16.h>

// Problem constants
#define BB 128
#define SS 512
#define EE 16
#define HH 256
#define G3 768
#define VV 256

typedef _Float16 half8 __attribute__((ext_vector_type(8)));
typedef _Float16 half4_t __attribute__((ext_vector_type(4)));
typedef float f32x4 __attribute__((ext_vector_type(4)));

// ---------------------------------------------------------------------------
// P: swizzle W_hh [256][768] and W_out [256][256] (fp32, row=K, col=N) into
// fp16 MFMA B-fragment order: flat idx = ((n_tile*8 + k_tile)*64 + lane)*8 + j
//   = n*4096 + k*512 + L*8 + j
// holding W[k_tile*32 + (lane>>4)*8 + j][n_tile*16 + (lane&15)].
// ---------------------------------------------------------------------------
__global__ __launch_bounds__(256) void swizzle_weights(
    const float* __restrict__ Whh, const float* __restrict__ Wout,
    _Float16* __restrict__ whh_swz, _Float16* __restrict__ wout_swz) {
  int t = blockIdx.x * 256 + threadIdx.x;
  if (t < 48 * 8 * 64 * 8) {  // 196608 elements of W_hh
    int j = t & 7, L = (t >> 3) & 63, k = (t >> 9) & 7, n = t >> 12;
    int row = k * 32 + (L >> 4) * 8 + j;
    int col = n * 16 + (L & 15);
    whh_swz[t] = (_Float16)Whh[row * G3 + col];
  }
  if (t < 16 * 8 * 64 * 8) {  // 65536 elements of W_out
    int j = t & 7, L = (t >> 3) & 63, k = (t >> 9) & 7, n = t >> 12;
    int row = k * 32 + (L >> 4) * 8 + j;
    int col = n * 16 + (L & 15);
    wout_swz[t] = (_Float16)Wout[row * VV + col];
  }
}

// ---------------------------------------------------------------------------
// K1: gi = emb[x] @ W_ih + b_ih (+ b_hh folded for r,z gates), written fp16 in
// the swizzled per-(batch-group, t) layout K2's lanes read with 8B loads.
// (Layout is wave-count independent; unchanged from the 16-wave K2.)
// ---------------------------------------------------------------------------
__global__ __launch_bounds__(256) void gi_kernel(
    const int* __restrict__ x, const float* __restrict__ embed,
    const float* __restrict__ W_ih, const float* __restrict__ b_ih,
    const float* __restrict__ b_hh, _Float16* __restrict__ gi_swz) {
  int gid = blockIdx.x;          // 0..1023
  int bg = gid >> 7;             // batch group 0..7
  int t0 = (gid & 127) * 4;      // 4 timesteps per block
  int tid = threadIdx.x;

  __shared__ __align__(16) float s_wih[EE * G3];      // 48 KB
  __shared__ __align__(16) float s_bias[G3];          // 3 KB
  __shared__ __align__(16) float s_emb16[4][16][EE];  // 4 KB
  __shared__ int s_x[4][16];

  for (int i = tid; i < EE * G3; i += 256) s_wih[i] = W_ih[i];
  for (int i = tid; i < G3; i += 256)
    s_bias[i] = b_ih[i] + (i < 512 ? b_hh[i] : 0.0f);  // fold b_hh for r,z only
  if (tid < 64) {
    int tt = tid >> 4, m = tid & 15;
    s_x[tt][m] = x[(bg * 16 + m) * SS + t0 + tt];
  }
  __syncthreads();
  for (int i = tid; i < 4 * 16 * EE; i += 256) {
    int tt = i >> 8, m = (i >> 4) & 15, e = i & 15;
    s_emb16[tt][m][e] = embed[s_x[tt][m] * EE + e];
  }
  __syncthreads();

  for (int cch = 0; cch < 3; cch++) {
    int gc = cch * 256 + tid;  // gate column
    float w[EE];
#pragma unroll
    for (int e = 0; e < EE; e++) w[e] = s_wih[e * G3 + gc];
    float bias = s_bias[gc];
    int wi = (gc >> 4) & 15, cc = gc & 15;
    int tilebase = (cch * 16 + wi) * 64;
    for (int tt = 0; tt < 4; tt++) {
      size_t gbase = (size_t)(bg * 512 + t0 + tt) * 12288;
#pragma unroll
      for (int mq = 0; mq < 4; mq++) {
        half4_t v;
#pragma unroll
        for (int r = 0; r < 4; r++) {
          int m = mq * 4 + r;
          float acc = bias;
#pragma unroll
          for (int e = 0; e < EE; e++) acc += s_emb16[tt][m][e] * w[e];
          v[r] = (_Float16)acc;
        }
        *(half4_t*)(gi_swz + gbase + (size_t)((tilebase + mq * 16 + cc) * 4)) = v;
      }
    }
  }
}

// ---------------------------------------------------------------------------
// K2: GRU recurrence — R7 restructure: 8 blocks x 512 threads (8 waves).
// Wave w owns TWO column tiles (cols w*32..w*32+32) for all 3 gates.
//
// Why 8 waves instead of 16:
//  * W_hh per-lane floor: 196608 halves / block lanes. At 1024 lanes = 96
//    VGPRs but the waves_per_eu(4,4) budget is only 128 total -> compiler
//    shuttled weights (VGPR_Count=64, ~550 VALU insts/wave/step observed vs
//    ~130 in source). At 512 lanes = 192 VGPRs under a 256-reg budget
//    (waves_per_eu(2,2), 2 waves/SIMD, 1 block/CU): weights live in regs and
//    feed MFMA directly. Tally: 192 wgt + 24 acc + 12 gi + 4 hp + ~20
//    addr/temps ~= 252 <= 256.
//  * A-fragment LDS duplication halves: every wave reads the same 8 KB
//    A-tile; 16 waves = 128 KB/step (~1100 cy at ~112B/cy), 8 waves = 64 KB.
//  * hp (the z-blend h_{t-1}) is the lane's OWN previous C-fragment ->
//    carried in registers, eliminating 4 ds_read_u16/wave/step.
// Numerics identical to the 16-wave version (same MFMA order, same fp16
// rounding points). Spill tripwire: WRITE_SIZE must stay 32768 KB.
// Static LDS = 16.9 KB (double-buffered fp16 h tile; pad 264 halves/row).
// ---------------------------------------------------------------------------
__global__ void __launch_bounds__(512)
__attribute__((amdgpu_waves_per_eu(2, 2)))
gru_kernel(
    const _Float16* __restrict__ gi_swz, const _Float16* __restrict__ whh_swz,
    const float* __restrict__ b_hh, _Float16* __restrict__ h_seq) {
  int bg = blockIdx.x;  // 0..7
  int tid = threadIdx.x;
  int w = tid >> 6, L = tid & 63;
  int q = L >> 4, c = L & 15;

  __shared__ __align__(16) _Float16 s_h[2][16][264];  // 16.9 KB

  // 48 B-fragments for this wave's two column tiles: [n][gate][k] (192 VGPR).
  half8 wB[2][3][8];
#pragma unroll
  for (int n = 0; n < 2; n++)
#pragma unroll
    for (int g = 0; g < 3; g++)
#pragma unroll
      for (int k = 0; k < 8; k++)
        wB[n][g][k] = *(const half8*)(
            whh_swz + (((size_t)((g * 16 + (2 * w + n)) * 8 + k) * 64 + L) * 8));

  // n-gate hidden bias (multiplied by r inside the step), one per column tile
  float bhn0 = b_hh[512 + w * 32 + c];
  float bhn1 = b_hh[512 + w * 32 + 16 + c];

  // zero both h buffers (h0 = 0): 8448 halves = 4224 uints
  for (int idx = tid; idx < (2 * 16 * 264) / 2; idx += 512)
    ((unsigned int*)s_h)[idx] = 0u;
  __syncthreads();

  // lane's own h_{t-1} C-fragment values, carried in registers (h0 = 0)
  half4_t hp0 = {(_Float16)0.f, (_Float16)0.f, (_Float16)0.f, (_Float16)0.f};
  half4_t hp1 = hp0;

  // h_seq flat offset for (batch row bg*16 + q*4, t=0, col w*32+c)
  unsigned hoff = (unsigned)(bg * 16 + q * 4) * (SS * HH) + (unsigned)(w * 32 + c);
  // gi base offset for this lane (advance by 12288/step); tile wi=2w+n lives
  // at g*4096 + (2w+n)*256 + L*4
  unsigned gio = (unsigned)(bg * 512) * 12288u + (unsigned)(w * 512 + L * 4);

  _Float16* hsrc = &s_h[0][0][0];
  _Float16* hdst = &s_h[1][0][0];
  const int aoff = c * 264 + q * 8;                 // av base (halves)
  const int woff = (q * 4) * 264 + w * 32 + c;      // write base n=0 (halves)

#pragma unroll 1
  for (int t = 0; t < SS; t++) {
    // gate-input loads (global; issued early, consumed in epilogue)
    half4_t gR0 = *(const half4_t*)(gi_swz + gio);
    half4_t gR1 = *(const half4_t*)(gi_swz + gio + 256u);
    half4_t gZ0 = *(const half4_t*)(gi_swz + gio + 4096u);
    half4_t gZ1 = *(const half4_t*)(gi_swz + gio + 4352u);
    half4_t gN0 = *(const half4_t*)(gi_swz + gio + 8192u);
    half4_t gN1 = *(const half4_t*)(gi_swz + gio + 8448u);

    f32x4 aR0 = {0.f, 0.f, 0.f, 0.f}, aZ0 = aR0, aN0 = aR0;
    f32x4 aR1 = aR0, aZ1 = aR0, aN1 = aR0;
#pragma unroll
    for (int k = 0; k < 8; k++) {
      half8 av = *(const half8*)(hsrc + aoff + k * 32);  // A[m=c][k*32+q*8+j]
      aR0 = __builtin_amdgcn_mfma_f32_16x16x32_f16(av, wB[0][0][k], aR0, 0, 0, 0);
      aZ0 = __builtin_amdgcn_mfma_f32_16x16x32_f16(av, wB[0][1][k], aZ0, 0, 0, 0);
      aN0 = __builtin_amdgcn_mfma_f32_16x16x32_f16(av, wB[0][2][k], aN0, 0, 0, 0);
      aR1 = __builtin_amdgcn_mfma_f32_16x16x32_f16(av, wB[1][0][k], aR1, 0, 0, 0);
      aZ1 = __builtin_amdgcn_mfma_f32_16x16x32_f16(av, wB[1][1][k], aZ1, 0, 0, 0);
      aN1 = __builtin_amdgcn_mfma_f32_16x16x32_f16(av, wB[1][2][k], aN1, 0, 0, 0);
    }

#pragma unroll
    for (int r = 0; r < 4; r++) {
      // n=0 tile (col w*32 + c)
      {
        float rg = aR0[r] + (float)gR0[r];
        rg = 1.f / (1.f + __expf(-rg));
        float zg = aZ0[r] + (float)gZ0[r];
        zg = 1.f / (1.f + __expf(-zg));
        float ng = (float)gN0[r] + rg * (aN0[r] + bhn0);
        ng = 2.f / (1.f + __expf(-2.f * ng)) - 1.f;  // tanh
        float hn = (1.f - zg) * ng + zg * (float)hp0[r];
        _Float16 h16 = (_Float16)hn;
        hp0[r] = h16;
        hdst[woff + r * 264] = h16;
        h_seq[(size_t)(hoff + (unsigned)r * 131072u)] = h16;
      }
      // n=1 tile (col w*32 + 16 + c)
      {
        float rg = aR1[r] + (float)gR1[r];
        rg = 1.f / (1.f + __expf(-rg));
        float zg = aZ1[r] + (float)gZ1[r];
        zg = 1.f / (1.f + __expf(-zg));
        float ng = (float)gN1[r] + rg * (aN1[r] + bhn1);
        ng = 2.f / (1.f + __expf(-2.f * ng)) - 1.f;  // tanh
        float hn = (1.f - zg) * ng + zg * (float)hp1[r];
        _Float16 h16 = (_Float16)hn;
        hp1[r] = h16;
        hdst[woff + r * 264 + 16] = h16;
        h_seq[(size_t)(hoff + (unsigned)r * 131072u + 16u)] = h16;
      }
    }
    __syncthreads();
    _Float16* tp = hsrc; hsrc = hdst; hdst = tp;
    gio += 12288u;
    hoff += (unsigned)HH;
  }
}

// ---------------------------------------------------------------------------
// K3: out = h_seq @ W_out + b_out via fp16 MFMA. 1024 blocks x 256 threads;
// block handles 64 bt-rows (wave w -> rows w*16..+16), full N=256 (16 tiles).
// Static LDS = 33 KB.  Output written fp32.
// ---------------------------------------------------------------------------
__global__ __launch_bounds__(256) void out_kernel(
    const _Float16* __restrict__ h_seq, const _Float16* __restrict__ wout_swz,
    const float* __restrict__ b_out, float* __restrict__ out) {
  int blk = blockIdx.x;
  int tid = threadIdx.x;
  int w = tid >> 6, L = tid & 63, q = L >> 4, c = L & 15;

  __shared__ __align__(16) _Float16 s_a[64 * 264];  // 33 KB

  const _Float16* src = h_seq + (size_t)blk * 64 * 256;
  for (int idx = tid; idx < (64 * 256) / 8; idx += 256) {
    int row = idx >> 5, kk = (idx & 31) * 8;
    *(half8*)(s_a + row * 264 + kk) = *(const half8*)(src + row * 256 + kk);
  }
  __syncthreads();

  half8 a[8];
#pragma unroll
  for (int k = 0; k < 8; k++)
    a[k] = *(const half8*)(s_a + (w * 16 + c) * 264 + k * 32 + q * 8);

  f32x4 acc[16];
#pragma unroll
  for (int n = 0; n < 16; n++) {
    f32x4 z = {0.f, 0.f, 0.f, 0.f};
    acc[n] = z;
#pragma unroll
    for (int k = 0; k < 8; k++) {
      half8 b = *(const half8*)(wout_swz + ((size_t)(n * 8 + k) * 64 + L) * 8);
      acc[n] = __builtin_amdgcn_mfma_f32_16x16x32_f16(a[k], b, acc[n], 0, 0, 0);
    }
  }
#pragma unroll
  for (int n = 0; n < 16; n++) {
    int v = n * 16 + c;
    float bo = b_out[v];
#pragma unroll
    for (int r = 0; r < 4; r++) {
      int bt = blk * 64 + w * 16 + q * 4 + r;
      out[(size_t)bt * 256 + v] = acc[n][r] + bo;
    }
  }
}

// ---------------------------------------------------------------------------
extern "C" void kernel_launch(void* const* d_in, const int* in_sizes, int n_in,
                              void* d_out, int out_size, void* d_ws, size_t ws_size,
                              hipStream_t stream) {
  const int*   x    = (const int*)d_in[0];
  const float* emb  = (const float*)d_in[1];
  const float* Wih  = (const float*)d_in[2];
  const float* bih  = (const float*)d_in[3];
  const float* Whh  = (const float*)d_in[4];
  const float* bhh  = (const float*)d_in[5];
  const float* Wout = (const float*)d_in[6];
  const float* bout = (const float*)d_in[7];

  char* ws = (char*)d_ws;
  // ws layout (134,742,016 B total):
  //   gi_swz   : 128*512*768 fp16 = 100,663,296 B
  //   whh_swz  : 196608 fp16      =     393,216 B
  //   wout_swz : 65536 fp16       =     131,072 B
  //   h_seq    : 128*512*256 fp16 =  33,554,432 B
  _Float16* gi_swz   = (_Float16*)(ws);
  _Float16* whh_swz  = (_Float16*)(ws + 100663296);
  _Float16* wout_swz = (_Float16*)(ws + 100663296 + 393216);
  _Float16* h_seq    = (_Float16*)(ws + 100663296 + 393216 + 131072);

  swizzle_weights<<<768, 256, 0, stream>>>(Whh, Wout, whh_swz, wout_swz);
  gi_kernel<<<1024, 256, 0, stream>>>(x, emb, Wih, bih, bhh, gi_swz);
  gru_kernel<<<8, 512, 0, stream>>>(gi_swz, whh_swz, bhh, h_seq);
  out_kernel<<<1024, 256, 0, stream>>>(h_seq, wout_swz, bout, (float*)d_out);
}